// Round 3
// baseline (317.560 us; speedup 1.0000x reference)
//
#include <hip/hip_runtime.h>
#include <math.h>

// Problem constants (fixed by the reference's setup_inputs)
#define OUTS 7
#define SAMP 14          // OUTS * RATIO
#define NCH 256
#define TOTAL_PER_ROI (NCH * OUTS * OUTS)   // 12544 = 49 * 256

__global__ __launch_bounds__(256) void roi_extract_kernel(
    const float* __restrict__ f0, const float* __restrict__ f1,
    const float* __restrict__ f2, const float* __restrict__ f3,
    const float* __restrict__ rois, float* __restrict__ out, int K)
{
    const int k = blockIdx.x;
    if (k >= K) return;
    const int tid = threadIdx.x;

    // RoI scalars (broadcast loads; every thread computes them — wave-uniform)
    const float rx1 = rois[0 * K + k];
    const float ry1 = rois[1 * K + k];
    const float rx2 = rois[2 * K + k];
    const float ry2 = rois[3 * K + k];

    // FPN level: floor(log2(sqrt(area)/56 + 1e-6)), clipped to [0,3]
    const float sroi = sqrtf((rx2 - rx1 + 1.0f) * (ry2 - ry1 + 1.0f));
    int lv = (int)floorf(log2f(sroi / 56.0f + 1e-6f));
    lv = lv < 0 ? 0 : (lv > 3 ? 3 : lv);

    const float* fbase;
    int H, W;
    float sc;
    switch (lv) {
        case 0:  fbase = f0; H = 200; W = 304; sc = 0.25f;    break;
        case 1:  fbase = f1; H = 100; W = 152; sc = 0.125f;   break;
        case 2:  fbase = f2; H = 50;  W = 76;  sc = 0.0625f;  break;
        default: fbase = f3; H = 25;  W = 38;  sc = 0.03125f; break;
    }
    const int HW = H * W;

    // Separable per-axis sample tables (14 points per axis)
    __shared__ int   sy0[SAMP], syh[SAMP], sx0[SAMP], sxh[SAMP];
    __shared__ float swy[SAMP], swx[SAMP];
    __shared__ int   svy[SAMP], svx[SAMP];

    if (tid < SAMP) {
        const int i = tid;
        const float y1s = ry1 * sc, y2s = ry2 * sc;
        const float roih = fmaxf(y2s - y1s, 1.0f);
        const float g = ((float)i + 0.5f) * 0.5f;       // (i+0.5)/RATIO
        const float ys = y1s + g * (roih / (float)OUTS);
        svy[i] = (ys >= -1.0f && ys <= (float)H) ? 1 : 0;
        const float y = fminf(fmaxf(ys, 0.0f), (float)(H - 1));
        const float y0f = floorf(y);
        const int y0 = (int)y0f;
        sy0[i] = y0;
        syh[i] = min(y0 + 1, H - 1);
        swy[i] = y - y0f;
    } else if (tid < 2 * SAMP) {
        const int i = tid - SAMP;
        const float x1s = rx1 * sc, x2s = rx2 * sc;
        const float roiw = fmaxf(x2s - x1s, 1.0f);
        const float g = ((float)i + 0.5f) * 0.5f;
        const float xs = x1s + g * (roiw / (float)OUTS);
        svx[i] = (xs >= -1.0f && xs <= (float)W) ? 1 : 0;
        const float x = fminf(fmaxf(xs, 0.0f), (float)(W - 1));
        const float x0f = floorf(x);
        const int x0 = (int)x0f;
        sx0[i] = x0;
        sxh[i] = min(x0 + 1, W - 1);
        swx[i] = x - x0f;
    }
    __syncthreads();

    // Each thread: 49 outputs, stride-256 over flat (c*49 + bin) — coalesced stores
    float* outk = out + (size_t)k * TOTAL_PER_ROI;
    for (int idx = tid; idx < TOTAL_PER_ROI; idx += 256) {
        const int c = idx / 49;
        const int bin = idx - c * 49;
        const int oh = bin / 7;
        const int ow = bin - oh * 7;
        const float* fc = fbase + (size_t)c * HW;

        float acc = 0.0f;
#pragma unroll
        for (int py = 0; py < 2; ++py) {
            const int sy = oh * 2 + py;
            if (!svy[sy]) continue;
            const int ya = sy0[sy] * W;
            const int yb = syh[sy] * W;
            const float wy = swy[sy];
            const float omy = 1.0f - wy;
#pragma unroll
            for (int px = 0; px < 2; ++px) {
                const int sx = ow * 2 + px;
                if (!svx[sx]) continue;
                const int xa = sx0[sx];
                const int xb = sxh[sx];
                const float wx = swx[sx];
                const float omx = 1.0f - wx;
                const float v00 = fc[ya + xa];
                const float v01 = fc[ya + xb];
                const float v10 = fc[yb + xa];
                const float v11 = fc[yb + xb];
                acc += v00 * omy * omx + v01 * omy * wx
                     + v10 * wy * omx + v11 * wy * wx;
            }
        }
        outk[idx] = acc * 0.25f;
    }
}

extern "C" void kernel_launch(void* const* d_in, const int* in_sizes, int n_in,
                              void* d_out, int out_size, void* d_ws, size_t ws_size,
                              hipStream_t stream) {
    const float* f0 = (const float*)d_in[0];
    const float* f1 = (const float*)d_in[1];
    const float* f2 = (const float*)d_in[2];
    const float* f3 = (const float*)d_in[3];
    const float* rois = (const float*)d_in[4];
    float* out = (float*)d_out;
    int K = in_sizes[4] / 4;
    if (K <= 0) return;

    roi_extract_kernel<<<K, 256, 0, stream>>>(f0, f1, f2, f3, rois, out, K);
}